// Round 1
// baseline (678.993 us; speedup 1.0000x reference)
//
#include <hip/hip_runtime.h>
#include <hip/hip_bf16.h>
#include <cstdint>

// Problem constants: B_=2048 windows, N=64 tokens, C=512, H=16 heads, hd=32, nW=64.
typedef __bf16 bf16;
typedef __bf16 bf16x8_t __attribute__((ext_vector_type(8)));
typedef __bf16 bf16x4_t __attribute__((ext_vector_type(4)));
typedef float  f32x4_t  __attribute__((ext_vector_type(4)));

#define MFMA16(a, b, c) __builtin_amdgcn_mfma_f32_16x16x32_bf16((a), (b), (c), 0, 0, 0)

// ---------------------------------------------------------------------------
// Kernel 1: convert weights to bf16 (qkv_w 1536x512, proj_w 512x512)
// ---------------------------------------------------------------------------
__global__ void k_wprep(const float* __restrict__ wq, const float* __restrict__ wp,
                        bf16* __restrict__ wqb, bf16* __restrict__ wpb) {
    int t = blockIdx.x * 256 + threadIdx.x;
    int stride = gridDim.x * 256;
    for (int i = t; i < 196608; i += stride) {          // 786432/4
        float4 v = ((const float4*)wq)[i];
        bf16x4_t o; o[0]=(bf16)v.x; o[1]=(bf16)v.y; o[2]=(bf16)v.z; o[3]=(bf16)v.w;
        ((bf16x4_t*)wqb)[i] = o;
    }
    for (int i = t; i < 65536; i += stride) {           // 262144/4
        float4 v = ((const float4*)wp)[i];
        bf16x4_t o; o[0]=(bf16)v.x; o[1]=(bf16)v.y; o[2]=(bf16)v.z; o[3]=(bf16)v.w;
        ((bf16x4_t*)wpb)[i] = o;
    }
}

// ---------------------------------------------------------------------------
// Kernel 2: fused QKV-projection + window attention.
// One block per window (2048 blocks, 256 threads = 4 waves).
// Wave w owns token rows [16w, 16w+16). xp strip kept in registers (16 frags).
// Per head: GEMM (64x96, K=512) -> q/k/v LDS -> S=QK^T -> softmax -> PV -> ao.
// ---------------------------------------------------------------------------
__global__ __launch_bounds__(256) void k_qkv_attn(
    const float* __restrict__ x,     // (2048,64,512) f32
    const float* __restrict__ pe,    // (64,512) f32
    const float* __restrict__ rpe,   // (16,64,64) f32
    const float* __restrict__ mask,  // (64,64,64) f32
    const float* __restrict__ qkv_b, // (1536,) f32
    const bf16*  __restrict__ wq,    // (1536,512) bf16
    bf16* __restrict__ ao)           // (2048,64,512) bf16 out
{
    __shared__ bf16 Ws[96 * 72];   // W tile  [96][64] padded to 72
    __shared__ bf16 qs[64 * 40];   // q       [64][32] padded to 40
    __shared__ bf16 ks[64 * 40];   // k       [64][32] padded to 40
    __shared__ bf16 vts[32 * 72];  // v^T     [32][64] padded to 72
    __shared__ bf16 ps[64 * 72];   // P       [64][64] padded to 72

    const int b    = blockIdx.x;
    const int tid  = threadIdx.x;
    const int lane = tid & 63;
    const int wave = tid >> 6;
    const int lr   = lane & 15;   // frag row/col within 16
    const int lg   = lane >> 4;   // k-group
    const int row0 = wave * 16;
    const int wi   = b & 63;      // window index for mask (b % nW)

    // ---- load xp strip into registers: a[kc] covers k = kc*32 + lg*8 .. +8
    bf16x8_t a[16];
    {
        const float* xr = x  + ((size_t)(b * 64 + row0 + lr)) * 512;
        const float* pr = pe + (size_t)(row0 + lr) * 512;
#pragma unroll
        for (int kc = 0; kc < 16; ++kc) {
            int k = kc * 32 + lg * 8;
            float4 x0 = *(const float4*)(xr + k);
            float4 x1 = *(const float4*)(xr + k + 4);
            float4 p0 = *(const float4*)(pr + k);
            float4 p1 = *(const float4*)(pr + k + 4);
            bf16x8_t v;
            v[0]=(bf16)(x0.x+p0.x); v[1]=(bf16)(x0.y+p0.y);
            v[2]=(bf16)(x0.z+p0.z); v[3]=(bf16)(x0.w+p0.w);
            v[4]=(bf16)(x1.x+p1.x); v[5]=(bf16)(x1.y+p1.y);
            v[6]=(bf16)(x1.z+p1.z); v[7]=(bf16)(x1.w+p1.w);
            a[kc] = v;
        }
    }

    const float SCALE = 0.17677669529663687f;  // 32^-0.5

    for (int h = 0; h < 16; ++h) {
        // ---------------- QKV head-GEMM: out 64 x 96 (q|k|v), K=512 ----------
        f32x4_t acc[6] = {};
#pragma unroll
        for (int kt = 0; kt < 8; ++kt) {   // BK=64; fully unrolled so a[kc] stays in regs
            // reg-stage W tile rows 0..95 (q:0-31,k:32-63,v:64-95), cols kt*64..+64
            bf16x8_t wst[3];
#pragma unroll
            for (int j = 0; j < 3; ++j) {
                int c = tid + 256 * j;            // 768 chunks of 8 elems
                int rr = c >> 3, i8 = (c & 7) * 8;
                int n = ((rr >> 5) << 9) + (h << 5) + (rr & 31);  // W row
                wst[j] = *(const bf16x8_t*)(wq + (size_t)n * 512 + kt * 64 + i8);
            }
            __syncthreads();   // prior reads of Ws done (also gates head hand-off)
#pragma unroll
            for (int j = 0; j < 3; ++j) {
                int c = tid + 256 * j;
                int rr = c >> 3, i8 = (c & 7) * 8;
                *(bf16x8_t*)&Ws[rr * 72 + i8] = wst[j];
            }
            __syncthreads();
#pragma unroll
            for (int k2 = 0; k2 < 2; ++k2) {
                const int kc = kt * 2 + k2;
#pragma unroll
                for (int j = 0; j < 6; ++j) {
                    bf16x8_t bfrag = *(const bf16x8_t*)&Ws[(j * 16 + lr) * 72 + k2 * 32 + lg * 8];
                    acc[j] = MFMA16(a[kc], bfrag, acc[j]);
                }
            }
        }

        // ---------------- bias + scatter q/k/v to LDS ------------------------
#pragma unroll
        for (int j = 0; j < 6; ++j) {
            int which = j >> 1;
            int colh  = (j & 1) * 16 + lr;          // 0..31 within head dim
            float bj = qkv_b[which * 512 + h * 32 + colh];
#pragma unroll
            for (int r = 0; r < 4; ++r) {
                int row = row0 + lg * 4 + r;
                float val = acc[j][r] + bj;
                if (which == 0)      qs[row * 40 + colh] = (bf16)val;
                else if (which == 1) ks[row * 40 + colh] = (bf16)val;
                else                 vts[colh * 72 + row] = (bf16)val;   // transposed
            }
        }
        __syncthreads();

        // ---------------- S = q k^T (strip 16 x 64), K=32 in one MFMA --------
        bf16x8_t aq = *(const bf16x8_t*)&qs[(row0 + lr) * 40 + lg * 8];
        f32x4_t s[4];
        f32x4_t zero = {};
#pragma unroll
        for (int j = 0; j < 4; ++j) {
            bf16x8_t bk = *(const bf16x8_t*)&ks[(j * 16 + lr) * 40 + lg * 8];
            s[j] = MFMA16(aq, bk, zero);
        }

        // ---------------- scale + rpe + mask, wave-parallel softmax ----------
        const float* rp = rpe  + ((size_t)h)  * 4096;
        const float* mp = mask + ((size_t)wi) * 4096;
        float pv_[4][4];
        float mx[4] = {-1e30f, -1e30f, -1e30f, -1e30f};
#pragma unroll
        for (int j = 0; j < 4; ++j) {
            int col = j * 16 + lr;
#pragma unroll
            for (int r = 0; r < 4; ++r) {
                int row = row0 + lg * 4 + r;
                float t = s[j][r] * SCALE + rp[row * 64 + col] + mp[row * 64 + col];
                pv_[j][r] = t;
                mx[r] = fmaxf(mx[r], t);
            }
        }
#pragma unroll
        for (int r = 0; r < 4; ++r) {   // row max across the 16-lane group
            float m = mx[r];
            m = fmaxf(m, __shfl_xor(m, 1));
            m = fmaxf(m, __shfl_xor(m, 2));
            m = fmaxf(m, __shfl_xor(m, 4));
            m = fmaxf(m, __shfl_xor(m, 8));
            mx[r] = m;
        }
        float sm[4] = {0.f, 0.f, 0.f, 0.f};
#pragma unroll
        for (int j = 0; j < 4; ++j)
#pragma unroll
            for (int r = 0; r < 4; ++r) {
                float e = __expf(pv_[j][r] - mx[r]);
                pv_[j][r] = e;
                sm[r] += e;
            }
#pragma unroll
        for (int r = 0; r < 4; ++r) {
            float ssum = sm[r];
            ssum += __shfl_xor(ssum, 1);
            ssum += __shfl_xor(ssum, 2);
            ssum += __shfl_xor(ssum, 4);
            ssum += __shfl_xor(ssum, 8);
            sm[r] = 1.0f / ssum;        // normalize after PV
        }
        // write unnormalized P (own strip only -> no barrier needed before PV)
#pragma unroll
        for (int j = 0; j < 4; ++j)
#pragma unroll
            for (int r = 0; r < 4; ++r)
                ps[(row0 + lg * 4 + r) * 72 + j * 16 + lr] = (bf16)pv_[j][r];

        // ---------------- O = P V (strip 16 x 32), K=64 ----------------------
        f32x4_t o[2] = {};
#pragma unroll
        for (int kh = 0; kh < 2; ++kh) {
            bf16x8_t pa = *(const bf16x8_t*)&ps[(row0 + lr) * 72 + kh * 32 + lg * 8];
#pragma unroll
            for (int jd = 0; jd < 2; ++jd) {
                bf16x8_t bv = *(const bf16x8_t*)&vts[(jd * 16 + lr) * 72 + kh * 32 + lg * 8];
                o[jd] = MFMA16(pa, bv, o[jd]);
            }
        }
        // ---------------- write ao (B_,N,C) bf16 -----------------------------
#pragma unroll
        for (int jd = 0; jd < 2; ++jd)
#pragma unroll
            for (int r = 0; r < 4; ++r) {
                int row = row0 + lg * 4 + r;
                ao[((size_t)(b * 64 + row)) * 512 + h * 32 + jd * 16 + lr] =
                    (bf16)(o[jd][r] * sm[r]);
            }
        // no trailing barrier needed: next head's LDS writes are gated by its
        // kt-loop barriers (all waves must finish this attention to pass them)
    }
}

// ---------------------------------------------------------------------------
// Kernel 3: proj GEMM. C[131072,512] = A[131072,512]@B^T[512,512] + bias, f32 out.
// 128x128 tile, BK=32, 4 waves, reg-staged LDS with +8 padding (2-way conflicts).
// ---------------------------------------------------------------------------
__global__ __launch_bounds__(256) void k_proj(
    const bf16* __restrict__ A, const bf16* __restrict__ Bw,
    const float* __restrict__ bias, float* __restrict__ C)
{
    __shared__ bf16 As[128 * 40];
    __shared__ bf16 Bs[128 * 40];

    const int tid  = threadIdx.x;
    const int lane = tid & 63;
    const int wave = tid >> 6;
    const int lr = lane & 15, lg = lane >> 4;
    const int wr = wave >> 1, wc = wave & 1;
    const int mb = blockIdx.x >> 2, nb = blockIdx.x & 3;
    const size_t m0 = (size_t)mb * 128;
    const int n0 = nb * 128;

    f32x4_t acc[4][4] = {};

    for (int kt = 0; kt < 16; ++kt) {
        const int k0 = kt * 32;
        // issue global loads before the barrier (overlap with prior compute)
        bf16x8_t va[2], vb[2];
#pragma unroll
        for (int j = 0; j < 2; ++j) {
            int c = tid + 256 * j;               // 512 chunks: row=c>>2, i8=(c&3)*8
            int row = c >> 2, i8 = (c & 3) * 8;
            va[j] = *(const bf16x8_t*)(A  + (m0 + row) * 512 + k0 + i8);
            vb[j] = *(const bf16x8_t*)(Bw + (size_t)(n0 + row) * 512 + k0 + i8);
        }
        __syncthreads();
#pragma unroll
        for (int j = 0; j < 2; ++j) {
            int c = tid + 256 * j;
            int row = c >> 2, i8 = (c & 3) * 8;
            *(bf16x8_t*)&As[row * 40 + i8] = va[j];
            *(bf16x8_t*)&Bs[row * 40 + i8] = vb[j];
        }
        __syncthreads();

        bf16x8_t af[4], bfr[4];
#pragma unroll
        for (int i = 0; i < 4; ++i)
            af[i] = *(const bf16x8_t*)&As[(wr * 64 + i * 16 + lr) * 40 + lg * 8];
#pragma unroll
        for (int j = 0; j < 4; ++j)
            bfr[j] = *(const bf16x8_t*)&Bs[(wc * 64 + j * 16 + lr) * 40 + lg * 8];
#pragma unroll
        for (int i = 0; i < 4; ++i)
#pragma unroll
            for (int j = 0; j < 4; ++j)
                acc[i][j] = MFMA16(af[i], bfr[j], acc[i][j]);
    }

    float bj[4];
#pragma unroll
    for (int j = 0; j < 4; ++j) bj[j] = bias[n0 + wc * 64 + j * 16 + lr];
#pragma unroll
    for (int i = 0; i < 4; ++i) {
#pragma unroll
        for (int j = 0; j < 4; ++j) {
            int col = n0 + wc * 64 + j * 16 + lr;
#pragma unroll
            for (int r = 0; r < 4; ++r) {
                size_t row = m0 + wr * 64 + i * 16 + lg * 4 + r;
                C[row * 512 + col] = acc[i][j][r] + bj[j];
            }
        }
    }
}

// ---------------------------------------------------------------------------
extern "C" void kernel_launch(void* const* d_in, const int* in_sizes, int n_in,
                              void* d_out, int out_size, void* d_ws, size_t ws_size,
                              hipStream_t stream) {
    (void)in_sizes; (void)n_in; (void)out_size; (void)ws_size;
    const float* x      = (const float*)d_in[0];
    const float* pe     = (const float*)d_in[1];
    const float* rpe    = (const float*)d_in[2];
    const float* mask   = (const float*)d_in[3];
    const float* qkv_w  = (const float*)d_in[4];
    const float* qkv_b  = (const float*)d_in[5];
    const float* proj_w = (const float*)d_in[6];
    const float* proj_b = (const float*)d_in[7];
    float* out = (float*)d_out;

    char* ws = (char*)d_ws;
    bf16* wqkvb  = (bf16*)ws;                    // 1,572,864 B
    bf16* wprojb = (bf16*)(ws + 1572864);        //   524,288 B
    bf16* ao     = (bf16*)(ws + 2097152);        // 134,217,728 B  (total ~130 MB)

    k_wprep<<<256, 256, 0, stream>>>(qkv_w, proj_w, wqkvb, wprojb);
    k_qkv_attn<<<2048, 256, 0, stream>>>(x, pe, rpe, mask, qkv_b, wqkvb, ao);
    k_proj<<<4096, 256, 0, stream>>>(ao, wprojb, proj_b, out);
}